// Round 1
// baseline (1563.697 us; speedup 1.0000x reference)
//
#include <hip/hip_runtime.h>

#define TT 512   // sequence length
#define BB 64    // batch
#define HH 128   // hidden
#define G4 512   // 4*H

__device__ __forceinline__ float fast_sigmoid(float x) {
    return 1.f / (1.f + __expf(-x));
}
__device__ __forceinline__ float fast_tanh(float x) {
    x = fminf(10.f, fmaxf(-10.f, x));
    float e = __expf(2.f * x);
    return (e - 1.f) / (e + 1.f);
}

// C[m,n] = sum_k A[m,k]*W[n,k] + b0[n] + b1[n];  A:(M,K) rm, W:(512,K) rm, C:(M,512) rm
template<int K>
__global__ __launch_bounds__(256) void gemm_pre(
    const float* __restrict__ A, const float* __restrict__ W,
    const float* __restrict__ b0, const float* __restrict__ b1,
    float* __restrict__ C)
{
    __shared__ float As[8][132];
    __shared__ float Ws[8][132];
    const int bm = blockIdx.x * 128;
    const int bn = blockIdx.y * 128;
    const int tid = threadIdx.x;
    const int tx = tid & 15;   // n micro
    const int ty = tid >> 4;   // m micro
    const int lr = tid >> 1;        // staging row 0..127
    const int lc = (tid & 1) * 4;   // staging col 0 or 4

    float acc[8][8];
    #pragma unroll
    for (int i = 0; i < 8; ++i)
        #pragma unroll
        for (int j = 0; j < 8; ++j) acc[i][j] = 0.f;

    for (int k0 = 0; k0 < K; k0 += 8) {
        float4 av = *(const float4*)&A[(size_t)(bm + lr) * K + k0 + lc];
        float4 wv = *(const float4*)&W[(size_t)(bn + lr) * K + k0 + lc];
        __syncthreads();
        As[lc+0][lr] = av.x; As[lc+1][lr] = av.y; As[lc+2][lr] = av.z; As[lc+3][lr] = av.w;
        Ws[lc+0][lr] = wv.x; Ws[lc+1][lr] = wv.y; Ws[lc+2][lr] = wv.z; Ws[lc+3][lr] = wv.w;
        __syncthreads();
        #pragma unroll
        for (int kk = 0; kk < 8; ++kk) {
            float a[8], w[8];
            *(float4*)&a[0] = *(const float4*)&As[kk][ty*8];
            *(float4*)&a[4] = *(const float4*)&As[kk][ty*8+4];
            *(float4*)&w[0] = *(const float4*)&Ws[kk][tx*8];
            *(float4*)&w[4] = *(const float4*)&Ws[kk][tx*8+4];
            #pragma unroll
            for (int i = 0; i < 8; ++i)
                #pragma unroll
                for (int j = 0; j < 8; ++j)
                    acc[i][j] = fmaf(a[i], w[j], acc[i][j]);
        }
    }
    #pragma unroll
    for (int i = 0; i < 8; ++i) {
        int m = bm + ty*8 + i;
        #pragma unroll
        for (int j = 0; j < 8; j += 4) {
            int n = bn + tx*8 + j;
            float4 v;
            v.x = acc[i][j]   + b0[n]   + b1[n];
            v.y = acc[i][j+1] + b0[n+1] + b1[n+1];
            v.z = acc[i][j+2] + b0[n+2] + b1[n+2];
            v.w = acc[i][j+3] + b0[n+3] + b1[n+3];
            *(float4*)&C[(size_t)m * G4 + n] = v;
        }
    }
}

// One WG per (direction, batch element). 512 threads; thread g owns w_hh row g in VGPRs.
// out[b, t, dir*128 + j] (row stride 256).
__global__ __launch_bounds__(512) void lstm_scan(
    const float* __restrict__ pre_f, const float* __restrict__ pre_b,
    const float* __restrict__ whh_f, const float* __restrict__ whh_b,
    float* __restrict__ out)
{
    const int dir = blockIdx.x >> 6;
    const int b   = blockIdx.x & 63;
    const float* __restrict__ pre  = dir ? pre_b : pre_f;
    const float* __restrict__ w_hh = dir ? whh_b : whh_f;
    const int t_ = threadIdx.x;      // gate index 0..511

    __shared__ float h_lds[HH];
    __shared__ float gates[G4];

    float w[HH];
    #pragma unroll
    for (int k = 0; k < HH; k += 4)
        *(float4*)&w[k] = *(const float4*)&w_hh[t_ * HH + k];

    float c = 0.f;
    if (t_ < HH) h_lds[t_] = 0.f;

    const size_t base = (size_t)b * TT * G4;
    float pbuf[4];
    #pragma unroll
    for (int s = 0; s < 4; ++s) {
        int tau = dir ? (TT - 1 - s) : s;
        pbuf[s] = pre[base + (size_t)tau * G4 + t_];
    }
    __syncthreads();

    for (int s0 = 0; s0 < TT; s0 += 4) {
        #pragma unroll
        for (int u = 0; u < 4; ++u) {
            const int s = s0 + u;
            float pv = pbuf[u];
            int sn = s + 4;
            if (sn < TT) {
                int taun = dir ? (TT - 1 - sn) : sn;
                pbuf[u] = pre[base + (size_t)taun * G4 + t_];
            }
            float acc = 0.f;
            #pragma unroll
            for (int k = 0; k < HH; k += 4) {
                float4 hh = *(const float4*)&h_lds[k];
                acc = fmaf(w[k],   hh.x, acc);
                acc = fmaf(w[k+1], hh.y, acc);
                acc = fmaf(w[k+2], hh.z, acc);
                acc = fmaf(w[k+3], hh.w, acc);
            }
            gates[t_] = pv + acc;
            __syncthreads();
            if (t_ < HH) {
                float gi = gates[t_];
                float gf = gates[HH + t_];
                float gg = gates[2*HH + t_];
                float go = gates[3*HH + t_];
                float si = fast_sigmoid(gi);
                float sf = fast_sigmoid(gf);
                float so = fast_sigmoid(go);
                float tg = fast_tanh(gg);
                c = sf * c + si * tg;
                float h = so * fast_tanh(c);
                h_lds[t_] = h;
                int tau = dir ? (TT - 1 - s) : s;
                out[((size_t)b * TT + tau) * (2*HH) + dir*HH + t_] = h;
            }
            __syncthreads();
        }
    }
}

// out[m,n] = b_fc[n] + sum_k h2[m,k]*w_fc[n,k];  h2:(32768,256), w_fc:(64,256)
__global__ __launch_bounds__(256) void fc_kernel(
    const float* __restrict__ h2, const float* __restrict__ w_fc,
    const float* __restrict__ b_fc, float* __restrict__ out)
{
    int idx = blockIdx.x * 256 + threadIdx.x;
    int m = idx >> 6;
    int n = idx & 63;
    const float4* hr = (const float4*)(h2 + (size_t)m * 256);
    const float4* wr = (const float4*)(w_fc + (size_t)n * 256);
    float acc = 0.f;
    #pragma unroll 8
    for (int k = 0; k < 64; ++k) {
        float4 a = hr[k];
        float4 w = wr[k];
        acc += a.x*w.x + a.y*w.y + a.z*w.z + a.w*w.w;
    }
    out[idx] = acc + b_fc[n];
}

extern "C" void kernel_launch(void* const* d_in, const int* in_sizes, int n_in,
                              void* d_out, int out_size, void* d_ws, size_t ws_size,
                              hipStream_t stream) {
    const float* x        = (const float*)d_in[0];
    const float* w_ih_l0  = (const float*)d_in[1];
    const float* w_hh_l0  = (const float*)d_in[2];
    const float* b_ih_l0  = (const float*)d_in[3];
    const float* b_hh_l0  = (const float*)d_in[4];
    const float* w_ih_l0r = (const float*)d_in[5];
    const float* w_hh_l0r = (const float*)d_in[6];
    const float* b_ih_l0r = (const float*)d_in[7];
    const float* b_hh_l0r = (const float*)d_in[8];
    const float* w_ih_l1  = (const float*)d_in[9];
    const float* w_hh_l1  = (const float*)d_in[10];
    const float* b_ih_l1  = (const float*)d_in[11];
    const float* b_hh_l1  = (const float*)d_in[12];
    const float* w_ih_l1r = (const float*)d_in[13];
    const float* w_hh_l1r = (const float*)d_in[14];
    const float* b_ih_l1r = (const float*)d_in[15];
    const float* b_hh_l1r = (const float*)d_in[16];
    const float* w_fc     = (const float*)d_in[17];
    const float* b_fc     = (const float*)d_in[18];

    float* ws    = (float*)d_ws;
    float* pre_f = ws;                       // 32768*512 = 16,777,216 floats
    float* pre_b = ws + 16777216;            // 16,777,216 floats
    float* out0  = ws + 2 * 16777216;        // 32768*256 = 8,388,608 floats
    float* out1  = out0 + 8388608;           // 8,388,608 floats
    // total 192 MB

    dim3 gg(256, 4);  // M/128 x 512/128

    // Layer 0
    gemm_pre<64><<<gg, 256, 0, stream>>>(x, w_ih_l0,  b_ih_l0,  b_hh_l0,  pre_f);
    gemm_pre<64><<<gg, 256, 0, stream>>>(x, w_ih_l0r, b_ih_l0r, b_hh_l0r, pre_b);
    lstm_scan<<<128, 512, 0, stream>>>(pre_f, pre_b, w_hh_l0, w_hh_l0r, out0);

    // Layer 1
    gemm_pre<256><<<gg, 256, 0, stream>>>(out0, w_ih_l1,  b_ih_l1,  b_hh_l1,  pre_f);
    gemm_pre<256><<<gg, 256, 0, stream>>>(out0, w_ih_l1r, b_ih_l1r, b_hh_l1r, pre_b);
    lstm_scan<<<128, 512, 0, stream>>>(pre_f, pre_b, w_hh_l1, w_hh_l1r, out1);

    // FC
    fc_kernel<<<(BB*TT*64)/256, 256, 0, stream>>>(out1, w_fc, b_fc, (float*)d_out);
}